// Round 13
// baseline (166.200 us; speedup 1.0000x reference)
//
#include <hip/hip_runtime.h>
#include <hip/hip_bf16.h>

#define NN 16384
#define EE 262144
#define GG 32
#define NPGC 512
#define NEG_SLOPE 0.2f

typedef __attribute__((ext_vector_type(8))) short bf16x8;
typedef __attribute__((ext_vector_type(4))) float f32x4;

__device__ __forceinline__ float b2f(short s) {
    union { float f; unsigned u; } c;
    c.u = ((unsigned)(unsigned short)s) << 16;
    return c.f;
}

__device__ __forceinline__ short f2b(float f) {
    __hip_bfloat16 b = __float2bfloat16(f);
    short r;
    __builtin_memcpy(&r, &b, 2);
    return r;
}

// ---------------- k1 prep: build_h (+zero deg) U wtrans0 U wtrans1 U wal1/war1 table ----------------
__global__ __launch_bounds__(320) void prep_kernel(
    const float* __restrict__ feat, const float* __restrict__ aa_emb,
    const int* __restrict__ ref_aa, const int* __restrict__ alt_aa,
    const int* __restrict__ graph_id, __hip_bfloat16* __restrict__ h,
    int* __restrict__ deg,
    const float* __restrict__ W0, const float* __restrict__ R0,
    const float* __restrict__ W1, const float* __restrict__ R1,
    __hip_bfloat16* __restrict__ wt0, __hip_bfloat16* __restrict__ wt1,
    const float* __restrict__ al1, const float* __restrict__ ar1,
    float* __restrict__ wal1, float* __restrict__ war1)
{
    int b = blockIdx.x, t = threadIdx.x;
    if (b < NN) {
        int n = b;
        if (t == 0) deg[n] = 0;
        float v;
        if (t < 64) {
            int ra = ref_aa[n], ga = alt_aa[graph_id[n]];
            v = aa_emb[ra * 64 + t] * aa_emb[ga * 64 + t];
        } else {
            v = feat[(size_t)n * 256 + (t - 64)];
        }
        h[(size_t)n * 320 + t] = __float2bfloat16(v);
    } else if (b < NN + 256) {
        int c = b - NN;   // layer0 col, K=320 == blockDim
        float v = (c < 128) ? W0[(size_t)t * 128 + c] : R0[(size_t)t * 128 + (c - 128)];
        wt0[(size_t)c * 320 + t] = __float2bfloat16(v);
    } else if (b < NN + 256 + 1024) {
        int cc = b - NN - 256;  // layer1 col, K=128
        if (t < 128) {
            float v = (cc < 512) ? W1[(size_t)t * 512 + cc] : R1[(size_t)t * 512 + (cc - 512)];
            wt1[(size_t)cc * 128 + t] = __float2bfloat16(v);
        }
    } else {
        // wal1[k][hh] = sum_o W1[k][hh*256+o] * al1[hh][o]  (f32 exact)
        if (t < 128) {
            for (int hh = 0; hh < 2; hh++) {
                float sl = 0.f, sr = 0.f;
                for (int o = 0; o < 256; o++) {
                    float w = W1[(size_t)t * 512 + hh * 256 + o];
                    sl += w * al1[hh * 256 + o];
                    sr += w * ar1[hh * 256 + o];
                }
                wal1[t * 2 + hh] = sl;
                war1[t * 2 + hh] = sr;
            }
        }
    }
}

// ---------------- MFMA GEMM body: split bf16 output [ftb | resb] ----------------
template<int FR, int C1, int KTOT>
__device__ __forceinline__ void gemm_body(
    const __hip_bfloat16* __restrict__ A, const __hip_bfloat16* __restrict__ Bt,
    __hip_bfloat16* __restrict__ ftb, __hip_bfloat16* __restrict__ resb,
    int bx, int by, short* lds)
{
    constexpr int BM = 32 * FR;
    short* As = lds;
    short* Bs = lds + BM * 64;
    int t = threadIdx.x;
    int wid = t >> 6, lane = t & 63;
    int wr = wid >> 1, wc = wid & 1;
    int row0 = bx * BM, col0 = by * BM;

    f32x4 acc[FR][FR];
#pragma unroll
    for (int m = 0; m < FR; m++)
#pragma unroll
        for (int n = 0; n < FR; n++) acc[m][n] = (f32x4){0.f, 0.f, 0.f, 0.f};

    for (int kk = 0; kk < KTOT; kk += 64) {
        __syncthreads();
#pragma unroll
        for (int c = t; c < BM * 8; c += 256) {
            int row = c >> 3, slot = c & 7;
            int sw = (slot ^ (row & 7)) * 8;
            bf16x8 va = *(const bf16x8*)(A + (size_t)(row0 + row) * KTOT + kk + slot * 8);
            *(bf16x8*)(&As[row * 64 + sw]) = va;
            bf16x8 vb = *(const bf16x8*)(Bt + (size_t)(col0 + row) * KTOT + kk + slot * 8);
            *(bf16x8*)(&Bs[row * 64 + sw]) = vb;
        }
        __syncthreads();
#pragma unroll
        for (int ks = 0; ks < 2; ks++) {
            int kslot = ks * 4 + (lane >> 4);
            bf16x8 a[FR], bfr[FR];
#pragma unroll
            for (int m = 0; m < FR; m++) {
                int row = wr * FR * 16 + m * 16 + (lane & 15);
                a[m] = *(const bf16x8*)(&As[row * 64 + ((kslot ^ (row & 7)) * 8)]);
            }
#pragma unroll
            for (int n = 0; n < FR; n++) {
                int col = wc * FR * 16 + n * 16 + (lane & 15);
                bfr[n] = *(const bf16x8*)(&Bs[col * 64 + ((kslot ^ (col & 7)) * 8)]);
            }
#pragma unroll
            for (int m = 0; m < FR; m++)
#pragma unroll
                for (int n = 0; n < FR; n++)
                    acc[m][n] = __builtin_amdgcn_mfma_f32_16x16x32_bf16(a[m], bfr[n], acc[m][n], 0, 0, 0);
        }
    }

#pragma unroll
    for (int m = 0; m < FR; m++)
#pragma unroll
        for (int n = 0; n < FR; n++) {
            int colg = col0 + wc * FR * 16 + n * 16 + (lane & 15);
            int rbase = row0 + wr * FR * 16 + m * 16 + (lane >> 4) * 4;
#pragma unroll
            for (int r = 0; r < 4; r++) {
                float v = acc[m][n][r];
                int rg = rbase + r;
                if (colg < C1) ftb[(size_t)rg * C1 + colg] = __float2bfloat16(v);
                else           resb[(size_t)rg * C1 + (colg - C1)] = __float2bfloat16(v);
            }
        }
}

// ---------------- k2: gemm0 (blocks 0..1023) U deg count (blocks 1024..2047) ----------------
__global__ __launch_bounds__(256) void gemm0_deg_kernel(
    const __hip_bfloat16* __restrict__ A, const __hip_bfloat16* __restrict__ Bt,
    __hip_bfloat16* __restrict__ ftb, __hip_bfloat16* __restrict__ resb,
    const int* __restrict__ dst, int* __restrict__ deg)
{
    __shared__ short lds[2 * 64 * 64];
    int b = blockIdx.x;
    if (b < 1024) {
        gemm_body<2, 128, 320>(A, Bt, ftb, resb, b & 255, b >> 8, lds);
    } else {
        int i = (b - 1024) * 256 + threadIdx.x;
        if (i < EE) atomicAdd(&deg[dst[i]], 1);
    }
}

// ---------------- gemm1 standalone ----------------
__global__ __launch_bounds__(256) void gemm1_kernel(
    const __hip_bfloat16* __restrict__ A, const __hip_bfloat16* __restrict__ Bt,
    __hip_bfloat16* __restrict__ ftb, __hip_bfloat16* __restrict__ resb)
{
    __shared__ short lds[2 * 128 * 64];
    gemm_body<4, 512, 128>(A, Bt, ftb, resb, blockIdx.x, blockIdx.y, lds);
}

// ---------------- k3: scan (block 0) U elr0 (blocks 1..8192) ----------------
__global__ __launch_bounds__(256) void scan_elr0_kernel(
    const int* __restrict__ deg, int* __restrict__ row, int* __restrict__ cursor,
    const __hip_bfloat16* __restrict__ ftb,
    const float* __restrict__ al, const float* __restrict__ ar,
    float* __restrict__ el, float* __restrict__ er)
{
    int b = blockIdx.x, t = threadIdx.x;
    if (b == 0) {
        __shared__ int part[256];
        __shared__ int pref[257];
        int base = t * 64;
        int s = 0;
        for (int i = 0; i < 64; i++) s += deg[base + i];
        part[t] = s;
        __syncthreads();
        if (t == 0) {
            int a = 0;
            for (int i = 0; i < 256; i++) { pref[i] = a; a += part[i]; }
            pref[256] = a;
        }
        __syncthreads();
        int a = pref[t];
        for (int i = 0; i < 64; i++) {
            row[base + i] = a; cursor[base + i] = a;
            a += deg[base + i];
        }
        if (t == 0) row[NN] = pref[256];
    } else {
        int gid = (b - 1) * 256 + t;
        int wv = gid >> 6, lane = gid & 63;
        int n = wv >> 1, hh = wv & 1;
        if (n >= NN) return;
        float f = b2f(((const short*)ftb)[(size_t)n * 128 + hh * 64 + lane]);
        float sl = f * al[hh * 64 + lane];
        float sr = f * ar[hh * 64 + lane];
#pragma unroll
        for (int d = 32; d; d >>= 1) { sl += __shfl_xor(sl, d); sr += __shfl_xor(sr, d); }
        if (lane == 0) { el[n * 2 + hh] = sl; er[n * 2 + hh] = sr; }
    }
}

// scatter src node ids directly into dst-sorted order
__global__ __launch_bounds__(256) void scatter_kernel(
    const int* __restrict__ src, const int* __restrict__ dst,
    int* __restrict__ cursor, int* __restrict__ srcs)
{
    int i = blockIdx.x * 256 + threadIdx.x;
    if (i < EE) {
        int p = atomicAdd(&cursor[dst[i]], 1);
        srcs[p] = src[i];
    }
}

// ---------------- k5: layer0 fused softmax+agg -> h1 (bf16) + fused el1/er1 ----------------
__global__ __launch_bounds__(256) void agg0_kernel(
    const __hip_bfloat16* __restrict__ ftb0, const __hip_bfloat16* __restrict__ resb0,
    const int* __restrict__ row, const int* __restrict__ srcs,
    const float* __restrict__ el, const float* __restrict__ er,
    const float* __restrict__ b0, __hip_bfloat16* __restrict__ h1,
    const float* __restrict__ wal1, const float* __restrict__ war1,
    float* __restrict__ el1, float* __restrict__ er1)
{
    int wv = (blockIdx.x * 256 + threadIdx.x) >> 6;
    int lane = threadIdx.x & 63;
    if (wv >= NN) return;
    int n = wv;
    int eo = lane >> 4, vo = lane & 15;
    int hh = vo >> 3, dim = vo * 8;
    int e0 = row[n], e1 = row[n + 1];
    float er0v = er[n * 2 + 0], er1v = er[n * 2 + 1];

    float acc[8] = {0.f, 0.f, 0.f, 0.f, 0.f, 0.f, 0.f, 0.f};
    float ts0 = 0.f, ts1 = 0.f;
    for (int base = e0; base < e1; base += 64) {
        int c = min(64, e1 - base);
        float w0 = 0.f, w1 = 0.f;
        int sm = -1;
        if (lane < c) {
            sm = srcs[base + lane];
            float v0 = el[sm * 2 + 0] + er0v; v0 = v0 > 0.f ? v0 : NEG_SLOPE * v0;
            float v1 = el[sm * 2 + 1] + er1v; v1 = v1 > 0.f ? v1 : NEG_SLOPE * v1;
            w0 = __expf(v0); w1 = __expf(v1);
        }
        ts0 += w0; ts1 += w1;
        for (int i = eo; i < c; i += 4) {
            int s = __shfl(sm, i);
            float a0 = __shfl(w0, i), a1 = __shfl(w1, i);
            float a = hh ? a1 : a0;
            bf16x8 v = *(const bf16x8*)((const short*)ftb0 + (size_t)s * 128 + dim);
#pragma unroll
            for (int j = 0; j < 8; j++) acc[j] += a * b2f(v[j]);
        }
    }
#pragma unroll
    for (int d = 32; d; d >>= 1) { ts0 += __shfl_xor(ts0, d); ts1 += __shfl_xor(ts1, d); }
#pragma unroll
    for (int j = 0; j < 8; j++) acc[j] += __shfl_xor(acc[j], 16);
#pragma unroll
    for (int j = 0; j < 8; j++) acc[j] += __shfl_xor(acc[j], 32);
    if (eo == 0) {
        float s = hh ? ts1 : ts0;
        float invv = s > 0.f ? 1.f / s : 0.f;
        bf16x8 res = *(const bf16x8*)((const short*)resb0 + (size_t)n * 128 + dim);
        bf16x8 o;
        float rr[8];
#pragma unroll
        for (int j = 0; j < 8; j++) {
            float r = acc[j] * invv + b2f(res[j]) + b0[dim + j];
            r = r > 0.f ? r : (__expf(r) - 1.f);
            rr[j] = r;
            o[j] = f2b(r);
        }
        *(bf16x8*)((short*)h1 + (size_t)n * 128 + dim) = o;

        // fused el1/er1 = h1_row . (W1 al1) across the 16 vo-lanes
        float pl0 = 0.f, pl1 = 0.f, pr0 = 0.f, pr1 = 0.f;
#pragma unroll
        for (int j = 0; j < 8; j++) {
            float x = rr[j];
            int k = dim + j;
            pl0 += x * wal1[k * 2 + 0]; pl1 += x * wal1[k * 2 + 1];
            pr0 += x * war1[k * 2 + 0]; pr1 += x * war1[k * 2 + 1];
        }
#pragma unroll
        for (int d = 1; d <= 8; d <<= 1) {
            pl0 += __shfl_xor(pl0, d); pl1 += __shfl_xor(pl1, d);
            pr0 += __shfl_xor(pr0, d); pr1 += __shfl_xor(pr1, d);
        }
        if (vo == 0) {
            el1[n * 2 + 0] = pl0; el1[n * 2 + 1] = pl1;
            er1[n * 2 + 0] = pr0; er1[n * 2 + 1] = pr1;
        }
    }
}

// ---------------- k7: layer1 fused softmax+agg + head-mean + ELU + block partial sums ----------------
__global__ __launch_bounds__(256) void agg1_kernel(
    const __hip_bfloat16* __restrict__ ftb1, const __hip_bfloat16* __restrict__ resb1,
    const int* __restrict__ row, const int* __restrict__ srcs,
    const float* __restrict__ el, const float* __restrict__ er,
    const float* __restrict__ b1, float* __restrict__ part)
{
    __shared__ float red[4][256];
    int t = threadIdx.x;
    int lane = t & 63, wid = t >> 6;
    int n = blockIdx.x * 4 + wid;
    int hh = lane >> 5, dim = lane * 8;
    int e0 = row[n], e1 = row[n + 1];
    float er0v = er[n * 2 + 0], er1v = er[n * 2 + 1];

    float acc[8] = {0.f, 0.f, 0.f, 0.f, 0.f, 0.f, 0.f, 0.f};
    float ts0 = 0.f, ts1 = 0.f;
    for (int base = e0; base < e1; base += 64) {
        int c = min(64, e1 - base);
        float w0 = 0.f, w1 = 0.f;
        int sm = -1;
        if (lane < c) {
            sm = srcs[base + lane];
            float v0 = el[sm * 2 + 0] + er0v; v0 = v0 > 0.f ? v0 : NEG_SLOPE * v0;
            float v1 = el[sm * 2 + 1] + er1v; v1 = v1 > 0.f ? v1 : NEG_SLOPE * v1;
            w0 = __expf(v0); w1 = __expf(v1);
        }
        ts0 += w0; ts1 += w1;
        int i = 0;
        for (; i + 4 <= c; i += 4) {
            int sA = __shfl(sm, i),     sB = __shfl(sm, i + 1);
            int sC = __shfl(sm, i + 2), sD = __shfl(sm, i + 3);
            float a0A = __shfl(w0, i),     a1A = __shfl(w1, i);
            float a0B = __shfl(w0, i + 1), a1B = __shfl(w1, i + 1);
            float a0C = __shfl(w0, i + 2), a1C = __shfl(w1, i + 2);
            float a0D = __shfl(w0, i + 3), a1D = __shfl(w1, i + 3);
            float aA = hh ? a1A : a0A, aB = hh ? a1B : a0B;
            float aC = hh ? a1C : a0C, aD = hh ? a1D : a0D;
            bf16x8 vA = *(const bf16x8*)((const short*)ftb1 + (size_t)sA * 512 + dim);
            bf16x8 vB = *(const bf16x8*)((const short*)ftb1 + (size_t)sB * 512 + dim);
            bf16x8 vC = *(const bf16x8*)((const short*)ftb1 + (size_t)sC * 512 + dim);
            bf16x8 vD = *(const bf16x8*)((const short*)ftb1 + (size_t)sD * 512 + dim);
#pragma unroll
            for (int j = 0; j < 8; j++) {
                acc[j] += aA * b2f(vA[j]) + aB * b2f(vB[j]) + aC * b2f(vC[j]) + aD * b2f(vD[j]);
            }
        }
        for (; i < c; i++) {
            int s = __shfl(sm, i);
            float a0 = __shfl(w0, i), a1 = __shfl(w1, i);
            float a = hh ? a1 : a0;
            bf16x8 v = *(const bf16x8*)((const short*)ftb1 + (size_t)s * 512 + dim);
#pragma unroll
            for (int j = 0; j < 8; j++) acc[j] += a * b2f(v[j]);
        }
    }
#pragma unroll
    for (int d = 32; d; d >>= 1) { ts0 += __shfl_xor(ts0, d); ts1 += __shfl_xor(ts1, d); }
    float s = hh ? ts1 : ts0;
    float invv = s > 0.f ? 1.f / s : 0.f;

    bf16x8 res = *(const bf16x8*)((const short*)resb1 + (size_t)n * 512 + dim);
    float r[8];
#pragma unroll
    for (int j = 0; j < 8; j++)
        r[j] = acc[j] * invv + b2f(res[j]) + b1[dim + j];
    float v[8];
#pragma unroll
    for (int j = 0; j < 8; j++) {
        float o = __shfl_xor(r[j], 32);
        v[j] = 0.5f * (r[j] + o);
    }
    if (lane < 32) {
#pragma unroll
        for (int j = 0; j < 8; j++) {
            float x = v[j];
            x = x > 0.f ? x : (__expf(x) - 1.f);
            red[wid][lane * 8 + j] = x;
        }
    }
    __syncthreads();
    part[(size_t)blockIdx.x * 256 + t] = red[0][t] + red[1][t] + red[2][t] + red[3][t];
}

// ---------------- k8: combine block partials + 3-layer MLP ----------------
__global__ __launch_bounds__(256) void readout2_kernel(
    const float* __restrict__ part,
    const float* __restrict__ mW0, const float* __restrict__ mb0,
    const float* __restrict__ mW1, const float* __restrict__ mb1,
    const float* __restrict__ mW2, const float* __restrict__ mb2,
    float* __restrict__ out)
{
    __shared__ float hg[256];
    __shared__ float x1[128];
    __shared__ float x2[64];
    int g = blockIdx.x, t = threadIdx.x;
    float s = 0.f;
    for (int c = 0; c < 128; c++) s += part[(size_t)(g * 128 + c) * 256 + t];
    hg[t] = s * (1.f / (float)NPGC);
    __syncthreads();
    if (t < 128) {
        float a = mb0[t];
        for (int k = 0; k < 256; k++) a += hg[k] * mW0[k * 128 + t];
        x1[t] = fmaxf(a, 0.f);
    }
    __syncthreads();
    if (t < 64) {
        float a = mb1[t];
        for (int k = 0; k < 128; k++) a += x1[k] * mW1[k * 64 + t];
        x2[t] = fmaxf(a, 0.f);
    }
    __syncthreads();
    if (t < 2) {
        float a = mb2[t];
        for (int k = 0; k < 64; k++) a += x2[k] * mW2[k * 2 + t];
        out[g * 2 + t] = a;
    }
}

extern "C" void kernel_launch(void* const* d_in, const int* in_sizes, int n_in,
                              void* d_out, int out_size, void* d_ws, size_t ws_size,
                              hipStream_t stream)
{
    const float* feat   = (const float*)d_in[0];
    const float* aa_emb = (const float*)d_in[1];
    const float* W0     = (const float*)d_in[2];
    const float* al0    = (const float*)d_in[3];
    const float* ar0    = (const float*)d_in[4];
    const float* res0   = (const float*)d_in[5];
    const float* b0     = (const float*)d_in[6];
    const float* W1     = (const float*)d_in[7];
    const float* al1    = (const float*)d_in[8];
    const float* ar1    = (const float*)d_in[9];
    const float* res1   = (const float*)d_in[10];
    const float* b1     = (const float*)d_in[11];
    const float* mW0    = (const float*)d_in[12];
    const float* mb0    = (const float*)d_in[13];
    const float* mW1    = (const float*)d_in[14];
    const float* mb1    = (const float*)d_in[15];
    const float* mW2    = (const float*)d_in[16];
    const float* mb2    = (const float*)d_in[17];
    const int* ref_aa   = (const int*)d_in[18];
    const int* alt_aa   = (const int*)d_in[19];
    const int* src      = (const int*)d_in[20];
    const int* dst      = (const int*)d_in[21];
    const int* graph_id = (const int*)d_in[22];
    float* out = (float*)d_out;

    size_t off = 0;
    auto alloc = [&](size_t bytes) -> void* {
        void* p = (char*)d_ws + off;
        off += (bytes + 255) & ~(size_t)255;
        return p;
    };
    __hip_bfloat16* h     = (__hip_bfloat16*)alloc((size_t)NN * 320 * 2);
    __hip_bfloat16* wt0   = (__hip_bfloat16*)alloc((size_t)256 * 320 * 2);
    __hip_bfloat16* wt1   = (__hip_bfloat16*)alloc((size_t)1024 * 128 * 2);
    __hip_bfloat16* ftb0  = (__hip_bfloat16*)alloc((size_t)NN * 128 * 2);
    __hip_bfloat16* resb0 = (__hip_bfloat16*)alloc((size_t)NN * 128 * 2);
    __hip_bfloat16* h1b   = (__hip_bfloat16*)alloc((size_t)NN * 128 * 2);
    __hip_bfloat16* ftb1  = (__hip_bfloat16*)alloc((size_t)NN * 512 * 2);
    __hip_bfloat16* resb1 = (__hip_bfloat16*)alloc((size_t)NN * 512 * 2);
    float* el0    = (float*)alloc((size_t)NN * 2 * 4);
    float* er0    = (float*)alloc((size_t)NN * 2 * 4);
    float* el1    = (float*)alloc((size_t)NN * 2 * 4);
    float* er1    = (float*)alloc((size_t)NN * 2 * 4);
    float* wal1   = (float*)alloc((size_t)128 * 2 * 4);
    float* war1   = (float*)alloc((size_t)128 * 2 * 4);
    int* deg      = (int*)alloc((size_t)NN * 4);
    int* row      = (int*)alloc((size_t)(NN + 1) * 4);
    int* cursor   = (int*)alloc((size_t)NN * 4);
    int* srcs     = (int*)alloc((size_t)EE * 4);
    float* part   = (float*)alloc((size_t)(NN / 4) * 256 * 4);

    (void)in_sizes; (void)n_in; (void)out_size; (void)ws_size;

    // k1: build_h + zero deg + weight transposes + wal1/war1 table
    prep_kernel<<<NN + 256 + 1024 + 1, 320, 0, stream>>>(
        feat, aa_emb, ref_aa, alt_aa, graph_id, h, deg, W0, res0, W1, res1, wt0, wt1,
        al1, ar1, wal1, war1);
    // k2: gemm0 U deg count
    gemm0_deg_kernel<<<2048, 256, 0, stream>>>(h, wt0, ftb0, resb0, dst, deg);
    // k3: scan U elr0
    scan_elr0_kernel<<<1 + 8192, 256, 0, stream>>>(deg, row, cursor, ftb0, al0, ar0, el0, er0);
    // k4: scatter
    scatter_kernel<<<EE / 256, 256, 0, stream>>>(src, dst, cursor, srcs);
    // k5: layer0 aggregation + fused el1/er1
    agg0_kernel<<<NN / 4, 256, 0, stream>>>(
        ftb0, resb0, row, srcs, el0, er0, b0, h1b, wal1, war1, el1, er1);
    // k6: gemm1
    gemm1_kernel<<<dim3(128, 8), 256, 0, stream>>>(h1b, wt1, ftb1, resb1);
    // k7: layer1 aggregation + block partial readout
    agg1_kernel<<<NN / 4, 256, 0, stream>>>(ftb1, resb1, row, srcs, el1, er1, b1, part);
    // k8: final readout + MLP
    readout2_kernel<<<GG, 256, 0, stream>>>(part, mW0, mb0, mW1, mb1, mW2, mb2, out);
}

// Round 14
// 148.676 us; speedup vs baseline: 1.1179x; 1.1179x over previous
//
#include <hip/hip_runtime.h>
#include <hip/hip_bf16.h>

#define NN 16384
#define EE 262144
#define GG 32
#define NPGC 512
#define NEG_SLOPE 0.2f

typedef __attribute__((ext_vector_type(8))) short bf16x8;
typedef __attribute__((ext_vector_type(4))) float f32x4;

__device__ __forceinline__ float b2f(short s) {
    union { float f; unsigned u; } c;
    c.u = ((unsigned)(unsigned short)s) << 16;
    return c.f;
}

__device__ __forceinline__ short f2b(float f) {
    __hip_bfloat16 b = __float2bfloat16(f);
    short r;
    __builtin_memcpy(&r, &b, 2);
    return r;
}

// ---------------- k1 prep: build_h (+zero deg) U wtrans(layer0) U wtrans(layer1) ----------------
__global__ __launch_bounds__(320) void prep_kernel(
    const float* __restrict__ feat, const float* __restrict__ aa_emb,
    const int* __restrict__ ref_aa, const int* __restrict__ alt_aa,
    const int* __restrict__ graph_id, __hip_bfloat16* __restrict__ h,
    int* __restrict__ deg,
    const float* __restrict__ W0, const float* __restrict__ R0,
    const float* __restrict__ W1, const float* __restrict__ R1,
    __hip_bfloat16* __restrict__ wt0, __hip_bfloat16* __restrict__ wt1)
{
    int b = blockIdx.x, t = threadIdx.x;
    if (b < NN) {
        int n = b;
        if (t == 0) deg[n] = 0;
        float v;
        if (t < 64) {
            int ra = ref_aa[n], ga = alt_aa[graph_id[n]];
            v = aa_emb[ra * 64 + t] * aa_emb[ga * 64 + t];
        } else {
            v = feat[(size_t)n * 256 + (t - 64)];
        }
        h[(size_t)n * 320 + t] = __float2bfloat16(v);
    } else if (b < NN + 256) {
        int c = b - NN;   // layer0 col, K=320 == blockDim
        float v = (c < 128) ? W0[(size_t)t * 128 + c] : R0[(size_t)t * 128 + (c - 128)];
        wt0[(size_t)c * 320 + t] = __float2bfloat16(v);
    } else {
        int cc = b - NN - 256;  // layer1 col, K=128
        if (t < 128) {
            float v = (cc < 512) ? W1[(size_t)t * 512 + cc] : R1[(size_t)t * 512 + (cc - 512)];
            wt1[(size_t)cc * 128 + t] = __float2bfloat16(v);
        }
    }
}

// ---------------- MFMA GEMM body: split bf16 output [ftb | resb] ----------------
template<int FR, int C1, int KTOT>
__device__ __forceinline__ void gemm_body(
    const __hip_bfloat16* __restrict__ A, const __hip_bfloat16* __restrict__ Bt,
    __hip_bfloat16* __restrict__ ftb, __hip_bfloat16* __restrict__ resb,
    int bx, int by, short* lds)
{
    constexpr int BM = 32 * FR;
    short* As = lds;
    short* Bs = lds + BM * 64;
    int t = threadIdx.x;
    int wid = t >> 6, lane = t & 63;
    int wr = wid >> 1, wc = wid & 1;
    int row0 = bx * BM, col0 = by * BM;

    f32x4 acc[FR][FR];
#pragma unroll
    for (int m = 0; m < FR; m++)
#pragma unroll
        for (int n = 0; n < FR; n++) acc[m][n] = (f32x4){0.f, 0.f, 0.f, 0.f};

    for (int kk = 0; kk < KTOT; kk += 64) {
        __syncthreads();
#pragma unroll
        for (int c = t; c < BM * 8; c += 256) {
            int row = c >> 3, slot = c & 7;
            int sw = (slot ^ (row & 7)) * 8;
            bf16x8 va = *(const bf16x8*)(A + (size_t)(row0 + row) * KTOT + kk + slot * 8);
            *(bf16x8*)(&As[row * 64 + sw]) = va;
            bf16x8 vb = *(const bf16x8*)(Bt + (size_t)(col0 + row) * KTOT + kk + slot * 8);
            *(bf16x8*)(&Bs[row * 64 + sw]) = vb;
        }
        __syncthreads();
#pragma unroll
        for (int ks = 0; ks < 2; ks++) {
            int kslot = ks * 4 + (lane >> 4);
            bf16x8 a[FR], bfr[FR];
#pragma unroll
            for (int m = 0; m < FR; m++) {
                int row = wr * FR * 16 + m * 16 + (lane & 15);
                a[m] = *(const bf16x8*)(&As[row * 64 + ((kslot ^ (row & 7)) * 8)]);
            }
#pragma unroll
            for (int n = 0; n < FR; n++) {
                int col = wc * FR * 16 + n * 16 + (lane & 15);
                bfr[n] = *(const bf16x8*)(&Bs[col * 64 + ((kslot ^ (col & 7)) * 8)]);
            }
#pragma unroll
            for (int m = 0; m < FR; m++)
#pragma unroll
                for (int n = 0; n < FR; n++)
                    acc[m][n] = __builtin_amdgcn_mfma_f32_16x16x32_bf16(a[m], bfr[n], acc[m][n], 0, 0, 0);
        }
    }

#pragma unroll
    for (int m = 0; m < FR; m++)
#pragma unroll
        for (int n = 0; n < FR; n++) {
            int colg = col0 + wc * FR * 16 + n * 16 + (lane & 15);
            int rbase = row0 + wr * FR * 16 + m * 16 + (lane >> 4) * 4;
#pragma unroll
            for (int r = 0; r < 4; r++) {
                float v = acc[m][n][r];
                int rg = rbase + r;
                if (colg < C1) ftb[(size_t)rg * C1 + colg] = __float2bfloat16(v);
                else           resb[(size_t)rg * C1 + (colg - C1)] = __float2bfloat16(v);
            }
        }
}

// ---------------- k2: gemm0 (blocks 0..1023) U deg count (blocks 1024..2047) ----------------
__global__ __launch_bounds__(256) void gemm0_deg_kernel(
    const __hip_bfloat16* __restrict__ A, const __hip_bfloat16* __restrict__ Bt,
    __hip_bfloat16* __restrict__ ftb, __hip_bfloat16* __restrict__ resb,
    const int* __restrict__ dst, int* __restrict__ deg)
{
    __shared__ short lds[2 * 64 * 64];
    int b = blockIdx.x;
    if (b < 1024) {
        gemm_body<2, 128, 320>(A, Bt, ftb, resb, b & 255, b >> 8, lds);
    } else {
        int i = (b - 1024) * 256 + threadIdx.x;
        if (i < EE) atomicAdd(&deg[dst[i]], 1);
    }
}

// ---------------- gemm1 standalone ----------------
__global__ __launch_bounds__(256) void gemm1_kernel(
    const __hip_bfloat16* __restrict__ A, const __hip_bfloat16* __restrict__ Bt,
    __hip_bfloat16* __restrict__ ftb, __hip_bfloat16* __restrict__ resb)
{
    __shared__ short lds[2 * 128 * 64];
    gemm_body<4, 512, 128>(A, Bt, ftb, resb, blockIdx.x, blockIdx.y, lds);
}

// ---------------- k3: scan (block 0) U elr0 (blocks 1..8192) ----------------
__global__ __launch_bounds__(256) void scan_elr0_kernel(
    const int* __restrict__ deg, int* __restrict__ row, int* __restrict__ cursor,
    const __hip_bfloat16* __restrict__ ftb,
    const float* __restrict__ al, const float* __restrict__ ar,
    float* __restrict__ el, float* __restrict__ er)
{
    int b = blockIdx.x, t = threadIdx.x;
    if (b == 0) {
        __shared__ int part[256];
        __shared__ int pref[257];
        int base = t * 64;
        int s = 0;
        for (int i = 0; i < 64; i++) s += deg[base + i];
        part[t] = s;
        __syncthreads();
        if (t == 0) {
            int a = 0;
            for (int i = 0; i < 256; i++) { pref[i] = a; a += part[i]; }
            pref[256] = a;
        }
        __syncthreads();
        int a = pref[t];
        for (int i = 0; i < 64; i++) {
            row[base + i] = a; cursor[base + i] = a;
            a += deg[base + i];
        }
        if (t == 0) row[NN] = pref[256];
    } else {
        int gid = (b - 1) * 256 + t;
        int wv = gid >> 6, lane = gid & 63;
        int n = wv >> 1, hh = wv & 1;
        if (n >= NN) return;
        float f = b2f(((const short*)ftb)[(size_t)n * 128 + hh * 64 + lane]);
        float sl = f * al[hh * 64 + lane];
        float sr = f * ar[hh * 64 + lane];
#pragma unroll
        for (int d = 32; d; d >>= 1) { sl += __shfl_xor(sl, d); sr += __shfl_xor(sr, d); }
        if (lane == 0) { el[n * 2 + hh] = sl; er[n * 2 + hh] = sr; }
    }
}

// scatter src node ids directly into dst-sorted order
__global__ __launch_bounds__(256) void scatter_kernel(
    const int* __restrict__ src, const int* __restrict__ dst,
    int* __restrict__ cursor, int* __restrict__ srcs)
{
    int i = blockIdx.x * 256 + threadIdx.x;
    if (i < EE) {
        int p = atomicAdd(&cursor[dst[i]], 1);
        srcs[p] = src[i];
    }
}

// ---------------- layer1 el/er: one wave per node, vectorized ----------------
__global__ __launch_bounds__(256) void elr1_kernel(
    const __hip_bfloat16* __restrict__ ftb,
    const float* __restrict__ al, const float* __restrict__ ar,
    float* __restrict__ el, float* __restrict__ er)
{
    int wv = (blockIdx.x * 256 + threadIdx.x) >> 6;
    int lane = threadIdx.x & 63;
    if (wv >= NN) return;
    int n = wv, hh = lane >> 5, dim = lane * 8;
    bf16x8 v = *(const bf16x8*)((const short*)ftb + (size_t)n * 512 + dim);
    float sl = 0.f, sr = 0.f;
#pragma unroll
    for (int j = 0; j < 8; j++) {
        float f = b2f(v[j]);
        sl += f * al[dim + j];
        sr += f * ar[dim + j];
    }
#pragma unroll
    for (int d = 16; d; d >>= 1) { sl += __shfl_xor(sl, d); sr += __shfl_xor(sr, d); }
    if ((lane & 31) == 0) { el[n * 2 + hh] = sl; er[n * 2 + hh] = sr; }
}

// ---------------- layer0 fused softmax+aggregation -> h1 (bf16) [R5 numerics] ----------------
__global__ __launch_bounds__(256) void agg0_kernel(
    const __hip_bfloat16* __restrict__ ftb0, const __hip_bfloat16* __restrict__ resb0,
    const int* __restrict__ row, const int* __restrict__ srcs,
    const float* __restrict__ el, const float* __restrict__ er,
    const float* __restrict__ b0, __hip_bfloat16* __restrict__ h1)
{
    int wv = (blockIdx.x * 256 + threadIdx.x) >> 6;
    int lane = threadIdx.x & 63;
    if (wv >= NN) return;
    int n = wv;
    int eo = lane >> 4, vo = lane & 15;
    int hh = vo >> 3, dim = vo * 8;
    int e0 = row[n], e1 = row[n + 1];
    float er0v = er[n * 2 + 0], er1v = er[n * 2 + 1];

    float acc[8] = {0.f, 0.f, 0.f, 0.f, 0.f, 0.f, 0.f, 0.f};
    float ts0 = 0.f, ts1 = 0.f;
    for (int base = e0; base < e1; base += 64) {
        int c = min(64, e1 - base);
        float w0 = 0.f, w1 = 0.f;
        int sm = -1;
        if (lane < c) {
            sm = srcs[base + lane];
            float v0 = el[sm * 2 + 0] + er0v; v0 = v0 > 0.f ? v0 : NEG_SLOPE * v0;
            float v1 = el[sm * 2 + 1] + er1v; v1 = v1 > 0.f ? v1 : NEG_SLOPE * v1;
            w0 = __expf(v0); w1 = __expf(v1);
        }
        ts0 += w0; ts1 += w1;
        for (int i = eo; i < c; i += 4) {
            int s = __shfl(sm, i);
            float a0 = __shfl(w0, i), a1 = __shfl(w1, i);
            float a = hh ? a1 : a0;
            bf16x8 v = *(const bf16x8*)((const short*)ftb0 + (size_t)s * 128 + dim);
#pragma unroll
            for (int j = 0; j < 8; j++) acc[j] += a * b2f(v[j]);
        }
    }
#pragma unroll
    for (int d = 32; d; d >>= 1) { ts0 += __shfl_xor(ts0, d); ts1 += __shfl_xor(ts1, d); }
#pragma unroll
    for (int j = 0; j < 8; j++) acc[j] += __shfl_xor(acc[j], 16);
#pragma unroll
    for (int j = 0; j < 8; j++) acc[j] += __shfl_xor(acc[j], 32);
    if (eo == 0) {
        float s = hh ? ts1 : ts0;
        float invv = s > 0.f ? 1.f / s : 0.f;
        bf16x8 res = *(const bf16x8*)((const short*)resb0 + (size_t)n * 128 + dim);
        bf16x8 o;
#pragma unroll
        for (int j = 0; j < 8; j++) {
            float r = acc[j] * invv + b2f(res[j]) + b0[dim + j];
            r = r > 0.f ? r : (__expf(r) - 1.f);
            o[j] = f2b(r);
        }
        *(bf16x8*)((short*)h1 + (size_t)n * 128 + dim) = o;
    }
}

// ---------------- layer1 fused softmax+agg + head-mean + ELU + block partial sums ----------------
__global__ __launch_bounds__(256) void agg1_kernel(
    const __hip_bfloat16* __restrict__ ftb1, const __hip_bfloat16* __restrict__ resb1,
    const int* __restrict__ row, const int* __restrict__ srcs,
    const float* __restrict__ el, const float* __restrict__ er,
    const float* __restrict__ b1, float* __restrict__ part)
{
    __shared__ float red[4][256];
    int t = threadIdx.x;
    int lane = t & 63, wid = t >> 6;
    int n = blockIdx.x * 4 + wid;
    int hh = lane >> 5, dim = lane * 8;
    int e0 = row[n], e1 = row[n + 1];
    float er0v = er[n * 2 + 0], er1v = er[n * 2 + 1];

    float acc[8] = {0.f, 0.f, 0.f, 0.f, 0.f, 0.f, 0.f, 0.f};
    float ts0 = 0.f, ts1 = 0.f;
    for (int base = e0; base < e1; base += 64) {
        int c = min(64, e1 - base);
        float w0 = 0.f, w1 = 0.f;
        int sm = -1;
        if (lane < c) {
            sm = srcs[base + lane];
            float v0 = el[sm * 2 + 0] + er0v; v0 = v0 > 0.f ? v0 : NEG_SLOPE * v0;
            float v1 = el[sm * 2 + 1] + er1v; v1 = v1 > 0.f ? v1 : NEG_SLOPE * v1;
            w0 = __expf(v0); w1 = __expf(v1);
        }
        ts0 += w0; ts1 += w1;
        int i = 0;
        for (; i + 4 <= c; i += 4) {
            int sA = __shfl(sm, i),     sB = __shfl(sm, i + 1);
            int sC = __shfl(sm, i + 2), sD = __shfl(sm, i + 3);
            float a0A = __shfl(w0, i),     a1A = __shfl(w1, i);
            float a0B = __shfl(w0, i + 1), a1B = __shfl(w1, i + 1);
            float a0C = __shfl(w0, i + 2), a1C = __shfl(w1, i + 2);
            float a0D = __shfl(w0, i + 3), a1D = __shfl(w1, i + 3);
            float aA = hh ? a1A : a0A, aB = hh ? a1B : a0B;
            float aC = hh ? a1C : a0C, aD = hh ? a1D : a0D;
            bf16x8 vA = *(const bf16x8*)((const short*)ftb1 + (size_t)sA * 512 + dim);
            bf16x8 vB = *(const bf16x8*)((const short*)ftb1 + (size_t)sB * 512 + dim);
            bf16x8 vC = *(const bf16x8*)((const short*)ftb1 + (size_t)sC * 512 + dim);
            bf16x8 vD = *(const bf16x8*)((const short*)ftb1 + (size_t)sD * 512 + dim);
#pragma unroll
            for (int j = 0; j < 8; j++) {
                acc[j] += aA * b2f(vA[j]) + aB * b2f(vB[j]) + aC * b2f(vC[j]) + aD * b2f(vD[j]);
            }
        }
        for (; i < c; i++) {
            int s = __shfl(sm, i);
            float a0 = __shfl(w0, i), a1 = __shfl(w1, i);
            float a = hh ? a1 : a0;
            bf16x8 v = *(const bf16x8*)((const short*)ftb1 + (size_t)s * 512 + dim);
#pragma unroll
            for (int j = 0; j < 8; j++) acc[j] += a * b2f(v[j]);
        }
    }
#pragma unroll
    for (int d = 32; d; d >>= 1) { ts0 += __shfl_xor(ts0, d); ts1 += __shfl_xor(ts1, d); }
    float s = hh ? ts1 : ts0;
    float invv = s > 0.f ? 1.f / s : 0.f;

    bf16x8 res = *(const bf16x8*)((const short*)resb1 + (size_t)n * 512 + dim);
    float r[8];
#pragma unroll
    for (int j = 0; j < 8; j++)
        r[j] = acc[j] * invv + b2f(res[j]) + b1[dim + j];
    float v[8];
#pragma unroll
    for (int j = 0; j < 8; j++) {
        float o = __shfl_xor(r[j], 32);
        v[j] = 0.5f * (r[j] + o);
    }
    if (lane < 32) {
#pragma unroll
        for (int j = 0; j < 8; j++) {
            float x = v[j];
            x = x > 0.f ? x : (__expf(x) - 1.f);
            red[wid][lane * 8 + j] = x;
        }
    }
    __syncthreads();
    part[(size_t)blockIdx.x * 256 + t] = red[0][t] + red[1][t] + red[2][t] + red[3][t];
}

// ---------------- readout: combine block partials + 3-layer MLP ----------------
__global__ __launch_bounds__(256) void readout2_kernel(
    const float* __restrict__ part,
    const float* __restrict__ mW0, const float* __restrict__ mb0,
    const float* __restrict__ mW1, const float* __restrict__ mb1,
    const float* __restrict__ mW2, const float* __restrict__ mb2,
    float* __restrict__ out)
{
    __shared__ float hg[256];
    __shared__ float x1[128];
    __shared__ float x2[64];
    int g = blockIdx.x, t = threadIdx.x;
    float s = 0.f;
    for (int c = 0; c < 128; c++) s += part[(size_t)(g * 128 + c) * 256 + t];
    hg[t] = s * (1.f / (float)NPGC);
    __syncthreads();
    if (t < 128) {
        float a = mb0[t];
        for (int k = 0; k < 256; k++) a += hg[k] * mW0[k * 128 + t];
        x1[t] = fmaxf(a, 0.f);
    }
    __syncthreads();
    if (t < 64) {
        float a = mb1[t];
        for (int k = 0; k < 128; k++) a += x1[k] * mW1[k * 64 + t];
        x2[t] = fmaxf(a, 0.f);
    }
    __syncthreads();
    if (t < 2) {
        float a = mb2[t];
        for (int k = 0; k < 64; k++) a += x2[k] * mW2[k * 2 + t];
        out[g * 2 + t] = a;
    }
}

extern "C" void kernel_launch(void* const* d_in, const int* in_sizes, int n_in,
                              void* d_out, int out_size, void* d_ws, size_t ws_size,
                              hipStream_t stream)
{
    const float* feat   = (const float*)d_in[0];
    const float* aa_emb = (const float*)d_in[1];
    const float* W0     = (const float*)d_in[2];
    const float* al0    = (const float*)d_in[3];
    const float* ar0    = (const float*)d_in[4];
    const float* res0   = (const float*)d_in[5];
    const float* b0     = (const float*)d_in[6];
    const float* W1     = (const float*)d_in[7];
    const float* al1    = (const float*)d_in[8];
    const float* ar1    = (const float*)d_in[9];
    const float* res1   = (const float*)d_in[10];
    const float* b1     = (const float*)d_in[11];
    const float* mW0    = (const float*)d_in[12];
    const float* mb0    = (const float*)d_in[13];
    const float* mW1    = (const float*)d_in[14];
    const float* mb1    = (const float*)d_in[15];
    const float* mW2    = (const float*)d_in[16];
    const float* mb2    = (const float*)d_in[17];
    const int* ref_aa   = (const int*)d_in[18];
    const int* alt_aa   = (const int*)d_in[19];
    const int* src      = (const int*)d_in[20];
    const int* dst      = (const int*)d_in[21];
    const int* graph_id = (const int*)d_in[22];
    float* out = (float*)d_out;

    size_t off = 0;
    auto alloc = [&](size_t bytes) -> void* {
        void* p = (char*)d_ws + off;
        off += (bytes + 255) & ~(size_t)255;
        return p;
    };
    __hip_bfloat16* h     = (__hip_bfloat16*)alloc((size_t)NN * 320 * 2);
    __hip_bfloat16* wt0   = (__hip_bfloat16*)alloc((size_t)256 * 320 * 2);
    __hip_bfloat16* wt1   = (__hip_bfloat16*)alloc((size_t)1024 * 128 * 2);
    __hip_bfloat16* ftb0  = (__hip_bfloat16*)alloc((size_t)NN * 128 * 2);
    __hip_bfloat16* resb0 = (__hip_bfloat16*)alloc((size_t)NN * 128 * 2);
    __hip_bfloat16* h1b   = (__hip_bfloat16*)alloc((size_t)NN * 128 * 2);
    __hip_bfloat16* ftb1  = (__hip_bfloat16*)alloc((size_t)NN * 512 * 2);
    __hip_bfloat16* resb1 = (__hip_bfloat16*)alloc((size_t)NN * 512 * 2);
    float* el0    = (float*)alloc((size_t)NN * 2 * 4);
    float* er0    = (float*)alloc((size_t)NN * 2 * 4);
    float* el1    = (float*)alloc((size_t)NN * 2 * 4);
    float* er1    = (float*)alloc((size_t)NN * 2 * 4);
    int* deg      = (int*)alloc((size_t)NN * 4);
    int* row      = (int*)alloc((size_t)(NN + 1) * 4);
    int* cursor   = (int*)alloc((size_t)NN * 4);
    int* srcs     = (int*)alloc((size_t)EE * 4);
    float* part   = (float*)alloc((size_t)(NN / 4) * 256 * 4);

    (void)in_sizes; (void)n_in; (void)out_size; (void)ws_size;

    // k1: build_h + zero deg + both weight transposes
    prep_kernel<<<NN + 256 + 1024, 320, 0, stream>>>(
        feat, aa_emb, ref_aa, alt_aa, graph_id, h, deg, W0, res0, W1, res1, wt0, wt1);
    // k2: gemm0 U deg count
    gemm0_deg_kernel<<<2048, 256, 0, stream>>>(h, wt0, ftb0, resb0, dst, deg);
    // k3: scan U elr0
    scan_elr0_kernel<<<1 + 8192, 256, 0, stream>>>(deg, row, cursor, ftb0, al0, ar0, el0, er0);
    // k4: scatter
    scatter_kernel<<<EE / 256, 256, 0, stream>>>(src, dst, cursor, srcs);
    // k5: layer0 aggregation
    agg0_kernel<<<NN / 4, 256, 0, stream>>>(ftb0, resb0, row, srcs, el0, er0, b0, h1b);
    // k6: gemm1
    gemm1_kernel<<<dim3(128, 8), 256, 0, stream>>>(h1b, wt1, ftb1, resb1);
    // k7: elr1
    elr1_kernel<<<NN / 4, 256, 0, stream>>>(ftb1, al1, ar1, el1, er1);
    // k8: layer1 aggregation + block partial readout
    agg1_kernel<<<NN / 4, 256, 0, stream>>>(ftb1, resb1, row, srcs, el1, er1, b1, part);
    // k9: final readout + MLP
    readout2_kernel<<<GG, 256, 0, stream>>>(part, mW0, mb0, mW1, mb1, mW2, mb2, out);
}